// Round 6
// baseline (205.332 us; speedup 1.0000x reference)
//
#include <hip/hip_runtime.h>
#include <math.h>

#define T_SEQ 2048
#define NH    32
#define NKV   8
#define HS    128
#define FD    64
#define NBLK  32          // T_SEQ / 64
#define EPSF  1e-12f
#define LDP   136         // k_main/k_fmap LDS row pitch (bf16 elems)

typedef unsigned short u16;
typedef __bf16 bf16x8 __attribute__((ext_vector_type(8)));
typedef float  f32x4  __attribute__((ext_vector_type(4)));

__device__ __forceinline__ u16 f2b(float f) {
  unsigned u = __builtin_bit_cast(unsigned, f);
  return (u16)((u + 0x7fffu + ((u >> 16) & 1u)) >> 16);
}

// ws layout (bytes):
//  fqb: bf16 [NH][NBLK][64 q][128 f]      16,777,216
//  FKT: bf16 [NH][128 f][T j]             16,777,216
//  ST : bf16 [NH][NBLK][144 d][128 f]     37,748,736  (row128=z; 129..143 unused)
//  VT : bf16 [NKV][128 d][T key]           4,194,304
//  WT : bf16 [2][NH][64 f][128 d]          1,048,576
//  QB : bf16 [NH][NBLK][64 q][128 d]      16,777,216   (bf16 Q tile images)
//  KBB: bf16 [NKV][NBLK][64 k][128 d]      4,194,304   (bf16 K tile images)
#define FQB_OFF 0
#define FKT_OFF 16777216
#define ST_OFF  33554432
#define VT_OFF  71303168
#define WT_OFF  75497472
#define QB_OFF  76546048
#define KB_OFF  93323264

// ---- staging helpers: 256 threads move one 64x128 bf16 tile (16 regs) ----
__device__ __forceinline__ void ldg_bf(uint4 r[4], const u16* __restrict__ src, int tid) {
#pragma unroll
  for (int i = 0; i < 4; ++i) r[i] = *(const uint4*)(src + tid * 8 + i * 2048);
}
__device__ __forceinline__ void sts_bf(u16* buf, const uint4 r[4], int tid) {
#pragma unroll
  for (int i = 0; i < 4; ++i) {
    int idx = tid * 8 + i * 2048, rr = idx >> 7, c = idx & 127;
    *(uint4*)(buf + rr * LDP + c) = r[i];
  }
}
__device__ __forceinline__ void ldg_vt(uint4 r[4], const u16* __restrict__ vts,
                                       int rofs, int kb0, int B, int tid) {
#pragma unroll
  for (int i = 0; i < 4; ++i) {
    int idx = tid * 8 + i * 2048, rr = (idx >> 7) + rofs, c = idx & 127;
    int key = (c < 64) ? (kb0 * 64 + c) : (B * 64 + (c - 64));
    r[i] = *(const uint4*)(vts + (size_t)rr * T_SEQ + key);
  }
}

// ---------------- K0: fused weight transpose + V transpose ----------------
// grid 320 blocks: [0,64) = WT transpose, [64,320) = VT transpose
__global__ __launch_bounds__(256) void k_pre(
    const float* __restrict__ wq, const float* __restrict__ wk,
    const float* __restrict__ vg,
    u16* __restrict__ WT, u16* __restrict__ VT)
{
  __shared__ float sB[128 * 68];
  const int bx = blockIdx.x, tid = threadIdx.x;

  if (bx < 64) {
    const int h = bx >> 1, isk = bx & 1;
    const float* src = (isk ? wk : wq) + (size_t)h * HS * FD;
    for (int idx = tid * 4; idx < 8192; idx += 1024) {
      int r = idx >> 6, c = idx & 63;
      *(float4*)(sB + r * 68 + c) = *(const float4*)(src + idx);
    }
    __syncthreads();
    u16* dst = WT + ((size_t)(isk * NH + h)) * 8192;
    for (int i = 0; i < 8; ++i) {
      int ch = tid + i * 256;
      int f = ch >> 5, d4 = (ch & 31) * 4;
      ushort4 u;
      u.x = f2b(sB[(d4 + 0) * 68 + f]);
      u.y = f2b(sB[(d4 + 1) * 68 + f]);
      u.z = f2b(sB[(d4 + 2) * 68 + f]);
      u.w = f2b(sB[(d4 + 3) * 68 + f]);
      *(ushort4*)(dst + f * 128 + d4) = u;
    }
  } else {
    const int idx2 = bx - 64;
    const int b = idx2 & 31, kvh = idx2 >> 5;
    float* sV = sB;                        // 64*129 floats
    for (int idx = tid * 4; idx < 8192; idx += 1024) {
      int r = idx >> 7, c = idx & 127;
      *(float4*)(sV + r * 129 + c) = *(const float4*)(vg + (size_t)(b * 64 + r) * (NKV * HS) + kvh * HS + c);
    }
    __syncthreads();
    const int lane = tid & 63, w = tid >> 6;
#pragma unroll
    for (int i = 0; i < 32; ++i) {
      int d = w * 32 + i;
      VT[((size_t)(kvh * 128 + d)) * T_SEQ + b * 64 + lane] = f2b(sV[lane * 129 + d]);
    }
  }
}

// ---------------- K1: feature maps (MFMA) + Q/K bf16 tile dump ----------------
__global__ __launch_bounds__(256) void k_fmap(
    const float* __restrict__ qg, const float* __restrict__ kg,
    const u16* __restrict__ WT,
    u16* __restrict__ fqb, u16* __restrict__ FKT,
    u16* __restrict__ QB, u16* __restrict__ KBB)
{
  __shared__ __align__(16) u16 smem[2 * 64 * 136];
  u16* sX = smem;              // X tile [q][d] pitch 136 ; later aliased as output buf
  u16* sW = smem + 64 * 136;   // WT rows [f][d] pitch 136
  const int lt = blockIdx.x, h = blockIdx.y, isk = blockIdx.z;
  const int tid = threadIdx.x, lane = tid & 63, w = tid >> 6;
  const int quad = lane >> 4, txn = lane & 15;

  const float* xbase = isk ? (kg + (h >> 2) * HS) : (qg + h * HS);
  const int    xstr  = isk ? (NKV * HS) : (NH * HS);
  for (int idx = tid * 4; idx < 8192; idx += 1024) {
    int r = idx >> 7, c = idx & 127;
    float4 v4 = *(const float4*)(xbase + (size_t)(lt * 64 + r) * xstr + c);
    ushort4 u; u.x = f2b(v4.x); u.y = f2b(v4.y); u.z = f2b(v4.z); u.w = f2b(v4.w);
    *(ushort4*)(sX + r * 136 + c) = u;
  }
  const u16* wt = WT + ((size_t)(isk * NH + h)) * 8192;
  for (int i = 0; i < 4; ++i) {
    int ch = tid + i * 256;
    int row = ch >> 4, d8 = (ch & 15) * 8;
    *(uint4*)(sW + row * 136 + d8) = *(const uint4*)(wt + row * 128 + d8);
  }
  __syncthreads();

  // dump the already-converted bf16 X tile for k_main (Q always; K once per kvh)
  if (!isk) {
    u16* ob = QB + ((size_t)(h * NBLK + lt)) * 8192;
    for (int i = 0; i < 4; ++i) {
      int ch = tid + i * 256;
      int row = ch >> 4, d8 = (ch & 15) * 8;
      *(uint4*)(ob + row * 128 + d8) = *(const uint4*)(sX + row * 136 + d8);
    }
  } else if ((h & 3) == 0) {
    u16* ob = KBB + ((size_t)((h >> 2) * NBLK + lt)) * 8192;
    for (int i = 0; i < 4; ++i) {
      int ch = tid + i * 256;
      int row = ch >> 4, d8 = (ch & 15) * 8;
      *(uint4*)(ob + row * 128 + d8) = *(const uint4*)(sX + row * 136 + d8);
    }
  }

  const int arow = w * 16 + txn;
  const f32x4 vzero = {0.f, 0.f, 0.f, 0.f};
  f32x4 zt[4] = {vzero, vzero, vzero, vzero};
#pragma unroll
  for (int ks = 0; ks < 4; ++ks) {
    bf16x8 a = *(const bf16x8*)(sX + arow * 136 + ks * 32 + quad * 8);
#pragma unroll
    for (int nt = 0; nt < 4; ++nt) {
      bf16x8 bb = *(const bf16x8*)(sW + (nt * 16 + txn) * 136 + ks * 32 + quad * 8);
      zt[nt] = __builtin_amdgcn_mfma_f32_16x16x32_bf16(a, bb, zt[nt], 0, 0, 0);
    }
  }

  float E1[4][4], E2[4][4];
#pragma unroll
  for (int r = 0; r < 4; ++r) {
    float zv[4];
    float mx = -1e30f, mn = 1e30f;
#pragma unroll
    for (int nt = 0; nt < 4; ++nt) {
      zv[nt] = zt[nt][r];
      mx = fmaxf(mx, zv[nt]); mn = fminf(mn, zv[nt]);
    }
#pragma unroll
    for (int o = 1; o < 16; o <<= 1) {
      mx = fmaxf(mx, __shfl_xor(mx, o));
      mn = fminf(mn, __shfl_xor(mn, o));
    }
    float e1[4], e2[4], s1 = 0.f, s2 = 0.f;
#pragma unroll
    for (int nt = 0; nt < 4; ++nt) {
      e1[nt] = __expf(zv[nt] - mx); s1 += e1[nt];
      e2[nt] = __expf(mn - zv[nt]); s2 += e2[nt];
    }
#pragma unroll
    for (int o = 1; o < 16; o <<= 1) { s1 += __shfl_xor(s1, o); s2 += __shfl_xor(s2, o); }
    float r1 = 1.f / s1, r2 = 1.f / s2;
#pragma unroll
    for (int nt = 0; nt < 4; ++nt) {
      E1[r][nt] = fmaxf(e1[nt] * r1, EPSF);
      E2[r][nt] = fmaxf(e2[nt] * r2, EPSF);
    }
  }

  __syncthreads();

  if (!isk) {
#pragma unroll
    for (int r = 0; r < 4; ++r) {
      int row = w * 16 + quad * 4 + r;
#pragma unroll
      for (int nt = 0; nt < 4; ++nt) {
        sX[row * 136 + nt * 16 + txn]      = f2b(E1[r][nt]);
        sX[row * 136 + 64 + nt * 16 + txn] = f2b(E2[r][nt]);
      }
    }
    __syncthreads();
    u16* ob = fqb + ((size_t)(h * NBLK + lt)) * 8192;
    for (int i = 0; i < 4; ++i) {
      int ch = tid + i * 256;
      int row = ch >> 4, f8 = (ch & 15) * 8;
      *(uint4*)(ob + row * 128 + f8) = *(const uint4*)(sX + row * 136 + f8);
    }
  } else {
#pragma unroll
    for (int r = 0; r < 4; ++r) {
      int j = w * 16 + quad * 4 + r;
#pragma unroll
      for (int nt = 0; nt < 4; ++nt) {
        sX[(nt * 16 + txn) * 68 + j]        = f2b(E1[r][nt]);
        sX[(nt * 16 + txn + 64) * 68 + j]   = f2b(E2[r][nt]);
      }
    }
    __syncthreads();
    u16* ob = FKT + (size_t)h * 128 * T_SEQ + lt * 64;
    for (int i = 0; i < 8; ++i) {
      int ch = tid + i * 256;
      int row = ch >> 4, j4 = (ch & 15) * 4;
      *(ushort4*)(ob + (size_t)row * T_SEQ + j4) = *(const ushort4*)(sX + row * 68 + j4);
    }
  }
}

// ---------------- K2: fused state + prefix scan (MFMA, 2 barriers/iter) ----------------
// grid (8 dchunk, 2 fhalf, NH), 256 thr = 4 waves; wave w owns n-tile w (16 f)
__global__ __launch_bounds__(256) void k_scan(
    const u16* __restrict__ FKT, const u16* __restrict__ VT, u16* __restrict__ ST)
{
  __shared__ __align__(16) u16 sVT[16 * 72];
  __shared__ __align__(16) u16 sFK[64 * 72];
  const int dc = blockIdx.x, fh = blockIdx.y, h = blockIdx.z;
  const int tid = threadIdx.x, lane = tid & 63, w = tid >> 6;
  const int quad = lane >> 4, txn = lane & 15;
  const bool doz = (dc == 0);

  bf16x8 vone;
#pragma unroll
  for (int j = 0; j < 8; ++j) vone[j] = (__bf16)1.0f;

  const u16* vbase = VT + ((size_t)((h >> 2) * 128 + dc * 16)) * T_SEQ;
  const u16* fbase = FKT + ((size_t)(h * 128 + fh * 64)) * T_SEQ;

  const int srow = tid >> 4, sj4 = (tid & 15) * 4;
  ushort4 rv, rf[4];
  rv = *(const ushort4*)(vbase + (size_t)srow * T_SEQ + sj4);
#pragma unroll
  for (int i = 0; i < 4; ++i) {
    int ch = tid + i * 256;
    int fr = ch >> 4, fj4 = (ch & 15) * 4;
    rf[i] = *(const ushort4*)(fbase + (size_t)fr * T_SEQ + fj4);
  }

  const f32x4 vzero = {0.f, 0.f, 0.f, 0.f};
  f32x4 acc = vzero, zacc = vzero;

  for (int b = 0; b < NBLK; ++b) {
    __syncthreads();            // prev-iter mfma reads done
    *(ushort4*)(sVT + srow * 72 + sj4) = rv;
#pragma unroll
    for (int i = 0; i < 4; ++i) {
      int ch = tid + i * 256;
      int fr = ch >> 4, fj4 = (ch & 15) * 4;
      *(ushort4*)(sFK + fr * 72 + fj4) = rf[i];
    }
    __syncthreads();
    if (b + 1 < NBLK) {         // prefetch next chunk during mfma + stores
      rv = *(const ushort4*)(vbase + (size_t)srow * T_SEQ + (b + 1) * 64 + sj4);
#pragma unroll
      for (int i = 0; i < 4; ++i) {
        int ch = tid + i * 256;
        int fr = ch >> 4, fj4 = (ch & 15) * 4;
        rf[i] = *(const ushort4*)(fbase + (size_t)fr * T_SEQ + (b + 1) * 64 + fj4);
      }
    }
#pragma unroll
    for (int ks = 0; ks < 2; ++ks) {
      bf16x8 a  = *(const bf16x8*)(sVT + txn * 72 + ks * 32 + quad * 8);
      bf16x8 bb = *(const bf16x8*)(sFK + (w * 16 + txn) * 72 + ks * 32 + quad * 8);
      acc = __builtin_amdgcn_mfma_f32_16x16x32_bf16(a, bb, acc, 0, 0, 0);
      if (doz) zacc = __builtin_amdgcn_mfma_f32_16x16x32_bf16(vone, bb, zacc, 0, 0, 0);
    }
    u16* Sb = ST + (((size_t)(h * NBLK + b)) * 144 + dc * 16) * 128 + fh * 64;
#pragma unroll
    for (int r = 0; r < 4; ++r)
      Sb[(quad * 4 + r) * 128 + w * 16 + txn] = f2b(acc[r]);
    if (doz && quad == 0)
      ST[(((size_t)(h * NBLK + b)) * 144 + 128) * 128 + fh * 64 + w * 16 + txn] = f2b(zacc[0]);
  }
}

// ---------------- K4: main attention (all-bf16 staging, 1-tile prefetch) ----------------
// grid (NBLK, NH), 256 threads = 4 waves; wave w owns q-rows [w*16, w*16+16)
__global__ __launch_bounds__(256, 4) void k_main(
    const u16* __restrict__ QB, const u16* __restrict__ KBB,
    const u16* __restrict__ fqb, const u16* __restrict__ ST, const u16* __restrict__ VT,
    const float* __restrict__ wfac, float* __restrict__ out)
{
  __shared__ __align__(16) u16 RA[64 * LDP];   // A-operand: FQ -> Q -> P (K-major rows)
  __shared__ __align__(16) u16 RB[64 * LDP];   // B-operand: S lo/hi -> K[B] -> K[B-1] -> V^T lo/hi
  __shared__ __align__(16) u16 sz[128];        // z row of S_cum
  const int B = blockIdx.x, h = blockIdx.y, tid = threadIdx.x;
  const int lane = tid & 63, w = tid >> 6;
  const int quad = lane >> 4, txn = lane & 15;
  const int arow = w * 16 + txn;
  const int koff = quad * 8;

  const f32x4 vzero = {0.f, 0.f, 0.f, 0.f};
  f32x4 y[8];
#pragma unroll
  for (int t = 0; t < 8; ++t) y[t] = vzero;
  float sln[4] = {0.f, 0.f, 0.f, 0.f};
  const bf16x8 bzero = {0, 0, 0, 0, 0, 0, 0, 0};

  const int kb0 = (B >= 1) ? B - 1 : 0;
  const u16* qtile = QB  + ((size_t)(h * NBLK + B)) * 8192;
  const u16* ktB   = KBB + ((size_t)((h >> 2) * NBLK + B)) * 8192;
  const u16* ktP   = KBB + ((size_t)((h >> 2) * NBLK + kb0)) * 8192;
  const u16* vts   = VT  + (size_t)((h >> 2) * 128) * T_SEQ;

  uint4 t0[4], t1[4];

  // ---- linear part: Y += FQ · S_cum[B-2]  (+ z -> sln) ----
  if (B >= 2) {
    const u16* fsrc = fqb + ((size_t)(h * NBLK + B)) * 8192;
    const u16* ssrc = ST + ((size_t)(h * NBLK + (B - 2))) * 18432;
    ldg_bf(t0, fsrc, tid);
    ldg_bf(t1, ssrc, tid);
    ushort4 zr;
    if (tid < 32) zr = *(const ushort4*)(ssrc + 16384 + tid * 4);
    sts_bf(RA, t0, tid);
    sts_bf(RB, t1, tid);
    if (tid < 32) *(ushort4*)(sz + tid * 4) = zr;
    ldg_bf(t0, ssrc + 8192, tid);            // prefetch S hi
    __syncthreads();                         // W1
    f32x4 yz = vzero;
#pragma unroll
    for (int ks = 0; ks < 4; ++ks) {
      bf16x8 a = *(const bf16x8*)(RA + arow * LDP + ks * 32 + koff);
#pragma unroll
      for (int t = 0; t < 4; ++t) {
        bf16x8 bb = *(const bf16x8*)(RB + (t * 16 + txn) * LDP + ks * 32 + koff);
        y[t] = __builtin_amdgcn_mfma_f32_16x16x32_bf16(a, bb, y[t], 0, 0, 0);
      }
      bf16x8 bz = (txn == 0) ? *(const bf16x8*)(sz + ks * 32 + koff) : bzero;
      yz = __builtin_amdgcn_mfma_f32_16x16x32_bf16(a, bz, yz, 0, 0, 0);
    }
    __syncthreads();                         // R1
    sts_bf(RB, t0, tid);                     // S hi
    ldg_bf(t0, qtile, tid);                  // prefetch Q tile (bf16)
    ldg_bf(t1, ktB, tid);                    // prefetch K[B] tile (bf16)
    __syncthreads();                         // W2
#pragma unroll
    for (int ks = 0; ks < 4; ++ks) {
      bf16x8 a = *(const bf16x8*)(RA + arow * LDP + ks * 32 + koff);
#pragma unroll
      for (int t = 4; t < 8; ++t) {
        bf16x8 bb = *(const bf16x8*)(RB + (t * 16 + txn - 64) * LDP + ks * 32 + koff);
        y[t] = __builtin_amdgcn_mfma_f32_16x16x32_bf16(a, bb, y[t], 0, 0, 0);
      }
    }
#pragma unroll
    for (int r = 0; r < 4; ++r) sln[r] = __shfl(yz[r], lane & 48);  // n==0 lane of quad
    __syncthreads();                         // R2
  } else {
    ldg_bf(t0, qtile, tid);
    ldg_bf(t1, ktB, tid);
  }

  // ---- stage Q->RA, K[B]->RB; prefetch K[B-1] ----
  sts_bf(RA, t0, tid);
  sts_bf(RB, t1, tid);
  ldg_bf(t0, ktP, tid);
  __syncthreads();                           // W3

  f32x4 s[8];
#pragma unroll
  for (int t = 0; t < 8; ++t) s[t] = vzero;
#pragma unroll
  for (int ks = 0; ks < 4; ++ks) {           // diagonal block -> s[4..7]
    bf16x8 a = *(const bf16x8*)(RA + arow * LDP + ks * 32 + koff);
#pragma unroll
    for (int t = 0; t < 4; ++t) {
      bf16x8 bb = *(const bf16x8*)(RB + (t * 16 + txn) * LDP + ks * 32 + koff);
      s[4 + t] = __builtin_amdgcn_mfma_f32_16x16x32_bf16(a, bb, s[4 + t], 0, 0, 0);
    }
  }

  if (B >= 1) {
    __syncthreads();                         // R3
    sts_bf(RB, t0, tid);                     // K[B-1]
    ldg_vt(t1, vts, 0, kb0, B, tid);         // prefetch V^T lo
    __syncthreads();                         // W4
#pragma unroll
    for (int ks = 0; ks < 4; ++ks) {         // previous block -> s[0..3]
      bf16x8 a = *(const bf16x8*)(RA + arow * LDP + ks * 32 + koff);
#pragma unroll
      for (int t = 0; t < 4; ++t) {
        bf16x8 bb = *(const bf16x8*)(RB + (t * 16 + txn) * LDP + ks * 32 + koff);
        s[t] = __builtin_amdgcn_mfma_f32_16x16x32_bf16(a, bb, s[t], 0, 0, 0);
      }
    }
  } else {
    ldg_vt(t1, vts, 0, kb0, B, tid);
  }

  // ---- masked softmax, write P (bf16) into RA rows (wave-private stripe) ----
  float wf = wfac[h];
  wf = 1.f / (1.f + __expf(-wf));
  const float scale = 0.08838834764831845f;
  float ssum[4];
#pragma unroll
  for (int r = 0; r < 4; ++r) {
    const int irow = w * 16 + quad * 4 + r;
    float sv[8];
    float m = -1e30f;
#pragma unroll
    for (int t = 0; t < 8; ++t) {
      float x = s[t][r] * scale;
      bool msk = (t < 4) ? (B == 0) : ((t - 4) * 16 + txn > irow);
      x = msk ? -1e30f : x;
      sv[t] = x;
      m = fmaxf(m, x);
    }
#pragma unroll
    for (int o = 1; o < 16; o <<= 1) m = fmaxf(m, __shfl_xor(m, o));
    float ss = 0.f;
#pragma unroll
    for (int t = 0; t < 8; ++t) {
      float e = (sv[t] > -1e29f) ? wf * __expf(sv[t] - m) : 0.f;
      ss += e;
      RA[irow * LDP + t * 16 + txn] = f2b(e);
    }
#pragma unroll
    for (int o = 1; o < 16; o <<= 1) ss += __shfl_xor(ss, o);
    ssum[r] = ss;
  }
  __syncthreads();                           // R4: all waves done reading RB

  // ---- V^T lo -> PV t=0..3; prefetch V^T hi ----
  sts_bf(RB, t1, tid);
  ldg_vt(t0, vts, 64, kb0, B, tid);
  __syncthreads();                           // W5
#pragma unroll
  for (int ks = 0; ks < 4; ++ks) {
    if (B == 0 && ks < 2) continue;          // P == 0 on prev-block keys
    bf16x8 a = *(const bf16x8*)(RA + arow * LDP + ks * 32 + koff);
#pragma unroll
    for (int t = 0; t < 4; ++t) {
      bf16x8 bb = *(const bf16x8*)(RB + (t * 16 + txn) * LDP + ks * 32 + koff);
      y[t] = __builtin_amdgcn_mfma_f32_16x16x32_bf16(a, bb, y[t], 0, 0, 0);
    }
  }
  __syncthreads();                           // R5

  // ---- V^T hi -> PV t=4..7 ----
  sts_bf(RB, t0, tid);
  __syncthreads();                           // W6
#pragma unroll
  for (int ks = 0; ks < 4; ++ks) {
    if (B == 0 && ks < 2) continue;
    bf16x8 a = *(const bf16x8*)(RA + arow * LDP + ks * 32 + koff);
#pragma unroll
    for (int t = 4; t < 8; ++t) {
      bf16x8 bb = *(const bf16x8*)(RB + (t * 16 + txn - 64) * LDP + ks * 32 + koff);
      y[t] = __builtin_amdgcn_mfma_f32_16x16x32_bf16(a, bb, y[t], 0, 0, 0);
    }
  }

  // ---- epilogue ----
  const size_t obase = ((size_t)h * T_SEQ + B * 64) * HS;
#pragma unroll
  for (int r = 0; r < 4; ++r) {
    float inv = 1.f / (ssum[r] + sln[r]);
    int irow = w * 16 + quad * 4 + r;
#pragma unroll
    for (int t = 0; t < 8; ++t)
      out[obase + (size_t)irow * HS + t * 16 + txn] = y[t][r] * inv;
  }
}

extern "C" void kernel_launch(void* const* d_in, const int* in_sizes, int n_in,
                              void* d_out, int out_size, void* d_ws, size_t ws_size,
                              hipStream_t stream) {
  const float* q    = (const float*)d_in[0];
  const float* k    = (const float*)d_in[1];
  const float* v    = (const float*)d_in[2];
  const float* wq   = (const float*)d_in[3];
  const float* wk   = (const float*)d_in[4];
  const float* wfac = (const float*)d_in[5];
  float* out = (float*)d_out;
  char* wsb = (char*)d_ws;

  u16* fqb = (u16*)(wsb + FQB_OFF);
  u16* FKT = (u16*)(wsb + FKT_OFF);
  u16* ST  = (u16*)(wsb + ST_OFF);
  u16* VT  = (u16*)(wsb + VT_OFF);
  u16* WT  = (u16*)(wsb + WT_OFF);
  u16* QB  = (u16*)(wsb + QB_OFF);
  u16* KBB = (u16*)(wsb + KB_OFF);

  k_pre  <<<dim3(320),         256, 0, stream>>>(wq, wk, v, WT, VT);
  k_fmap <<<dim3(NBLK, NH, 2), 256, 0, stream>>>(q, k, WT, fqb, FKT, QB, KBB);
  k_scan <<<dim3(8, 2, NH),    256, 0, stream>>>(FKT, VT, ST);
  k_main <<<dim3(NBLK, NH),    256, 0, stream>>>(QB, KBB, fqb, ST, VT, wfac, out);
}

// Round 7
// 169.444 us; speedup vs baseline: 1.2118x; 1.2118x over previous
//
#include <hip/hip_runtime.h>
#include <math.h>

#define T_SEQ 2048
#define NH    32
#define NKV   8
#define HS    128
#define FD    64
#define NBLK  32          // T_SEQ / 64
#define EPSF  1e-12f
#define LDP   136         // k_main/k_fmap LDS row pitch (bf16 elems)

typedef unsigned short u16;
typedef __bf16 bf16x8 __attribute__((ext_vector_type(8)));
typedef float  f32x4  __attribute__((ext_vector_type(4)));

__device__ __forceinline__ u16 f2b(float f) {
  unsigned u = __builtin_bit_cast(unsigned, f);
  return (u16)((u + 0x7fffu + ((u >> 16) & 1u)) >> 16);
}

// ws layout (bytes):
//  fqb: bf16 [NH][NBLK][64 q][128 f]      16,777,216
//  FKT: bf16 [NH][128 f][T j]             16,777,216
//  ST : bf16 [NH][NBLK][144 d][128 f]     37,748,736  (row128=z; 129..143 unused)
//  VT : bf16 [NKV][128 d][T key]           4,194,304
//  WT : bf16 [2][NH][64 f][128 d]          1,048,576
//  QB : bf16 [NH][NBLK][64 q][128 d]      16,777,216   (bf16 Q tile images)
//  KBB: bf16 [NKV][NBLK][64 k][128 d]      4,194,304   (bf16 K tile images)
#define FQB_OFF 0
#define FKT_OFF 16777216
#define ST_OFF  33554432
#define VT_OFF  71303168
#define WT_OFF  75497472
#define QB_OFF  76546048
#define KB_OFF  93323264

// ---- in-phase staging: contiguous bf16 64x128 tile -> LDS (pitch LDP) ----
__device__ __forceinline__ void stage_bf(u16* buf, const u16* __restrict__ src, int tid) {
#pragma unroll
  for (int i = 0; i < 4; ++i) {
    int idx = tid * 8 + i * 2048, rr = idx >> 7, c = idx & 127;
    *(uint4*)(buf + rr * LDP + c) = *(const uint4*)(src + idx);
  }
}
// V^T rows (stride T_SEQ), key window remap -> LDS
__device__ __forceinline__ void stage_vt(u16* buf, const u16* __restrict__ vts,
                                         int rofs, int kb0, int B, int tid) {
#pragma unroll
  for (int i = 0; i < 4; ++i) {
    int idx = tid * 8 + i * 2048, rr = idx >> 7, c = idx & 127;
    int key = (c < 64) ? (kb0 * 64 + c) : (B * 64 + (c - 64));
    *(uint4*)(buf + rr * LDP + c) = *(const uint4*)(vts + (size_t)(rr + rofs) * T_SEQ + key);
  }
}

// ---------------- K0: fused weight transpose + V transpose ----------------
// grid 320 blocks: [0,64) = WT transpose, [64,320) = VT transpose
__global__ __launch_bounds__(256) void k_pre(
    const float* __restrict__ wq, const float* __restrict__ wk,
    const float* __restrict__ vg,
    u16* __restrict__ WT, u16* __restrict__ VT)
{
  __shared__ float sB[128 * 68];
  const int bx = blockIdx.x, tid = threadIdx.x;

  if (bx < 64) {
    const int h = bx >> 1, isk = bx & 1;
    const float* src = (isk ? wk : wq) + (size_t)h * HS * FD;
    for (int idx = tid * 4; idx < 8192; idx += 1024) {
      int r = idx >> 6, c = idx & 63;
      *(float4*)(sB + r * 68 + c) = *(const float4*)(src + idx);
    }
    __syncthreads();
    u16* dst = WT + ((size_t)(isk * NH + h)) * 8192;
    for (int i = 0; i < 8; ++i) {
      int ch = tid + i * 256;
      int f = ch >> 5, d4 = (ch & 31) * 4;
      ushort4 u;
      u.x = f2b(sB[(d4 + 0) * 68 + f]);
      u.y = f2b(sB[(d4 + 1) * 68 + f]);
      u.z = f2b(sB[(d4 + 2) * 68 + f]);
      u.w = f2b(sB[(d4 + 3) * 68 + f]);
      *(ushort4*)(dst + f * 128 + d4) = u;
    }
  } else {
    const int idx2 = bx - 64;
    const int b = idx2 & 31, kvh = idx2 >> 5;
    float* sV = sB;                        // 64*129 floats
    for (int idx = tid * 4; idx < 8192; idx += 1024) {
      int r = idx >> 7, c = idx & 127;
      *(float4*)(sV + r * 129 + c) = *(const float4*)(vg + (size_t)(b * 64 + r) * (NKV * HS) + kvh * HS + c);
    }
    __syncthreads();
    const int lane = tid & 63, w = tid >> 6;
#pragma unroll
    for (int i = 0; i < 32; ++i) {
      int d = w * 32 + i;
      VT[((size_t)(kvh * 128 + d)) * T_SEQ + b * 64 + lane] = f2b(sV[lane * 129 + d]);
    }
  }
}

// ---------------- K1: feature maps (MFMA) + Q/K bf16 tile dump ----------------
__global__ __launch_bounds__(256) void k_fmap(
    const float* __restrict__ qg, const float* __restrict__ kg,
    const u16* __restrict__ WT,
    u16* __restrict__ fqb, u16* __restrict__ FKT,
    u16* __restrict__ QB, u16* __restrict__ KBB)
{
  __shared__ __align__(16) u16 smem[2 * 64 * 136];
  u16* sX = smem;              // X tile [q][d] pitch 136 ; later aliased as output buf
  u16* sW = smem + 64 * 136;   // WT rows [f][d] pitch 136
  const int lt = blockIdx.x, h = blockIdx.y, isk = blockIdx.z;
  const int tid = threadIdx.x, lane = tid & 63, w = tid >> 6;
  const int quad = lane >> 4, txn = lane & 15;

  const float* xbase = isk ? (kg + (h >> 2) * HS) : (qg + h * HS);
  const int    xstr  = isk ? (NKV * HS) : (NH * HS);
  for (int idx = tid * 4; idx < 8192; idx += 1024) {
    int r = idx >> 7, c = idx & 127;
    float4 v4 = *(const float4*)(xbase + (size_t)(lt * 64 + r) * xstr + c);
    ushort4 u; u.x = f2b(v4.x); u.y = f2b(v4.y); u.z = f2b(v4.z); u.w = f2b(v4.w);
    *(ushort4*)(sX + r * 136 + c) = u;
  }
  const u16* wt = WT + ((size_t)(isk * NH + h)) * 8192;
  for (int i = 0; i < 4; ++i) {
    int ch = tid + i * 256;
    int row = ch >> 4, d8 = (ch & 15) * 8;
    *(uint4*)(sW + row * 136 + d8) = *(const uint4*)(wt + row * 128 + d8);
  }
  __syncthreads();

  // dump the already-converted bf16 X tile for k_main (Q always; K once per kvh)
  if (!isk) {
    u16* ob = QB + ((size_t)(h * NBLK + lt)) * 8192;
    for (int i = 0; i < 4; ++i) {
      int ch = tid + i * 256;
      int row = ch >> 4, d8 = (ch & 15) * 8;
      *(uint4*)(ob + row * 128 + d8) = *(const uint4*)(sX + row * 136 + d8);
    }
  } else if ((h & 3) == 0) {
    u16* ob = KBB + ((size_t)((h >> 2) * NBLK + lt)) * 8192;
    for (int i = 0; i < 4; ++i) {
      int ch = tid + i * 256;
      int row = ch >> 4, d8 = (ch & 15) * 8;
      *(uint4*)(ob + row * 128 + d8) = *(const uint4*)(sX + row * 136 + d8);
    }
  }

  const int arow = w * 16 + txn;
  const f32x4 vzero = {0.f, 0.f, 0.f, 0.f};
  f32x4 zt[4] = {vzero, vzero, vzero, vzero};
#pragma unroll
  for (int ks = 0; ks < 4; ++ks) {
    bf16x8 a = *(const bf16x8*)(sX + arow * 136 + ks * 32 + quad * 8);
#pragma unroll
    for (int nt = 0; nt < 4; ++nt) {
      bf16x8 bb = *(const bf16x8*)(sW + (nt * 16 + txn) * 136 + ks * 32 + quad * 8);
      zt[nt] = __builtin_amdgcn_mfma_f32_16x16x32_bf16(a, bb, zt[nt], 0, 0, 0);
    }
  }

  float E1[4][4], E2[4][4];
#pragma unroll
  for (int r = 0; r < 4; ++r) {
    float zv[4];
    float mx = -1e30f, mn = 1e30f;
#pragma unroll
    for (int nt = 0; nt < 4; ++nt) {
      zv[nt] = zt[nt][r];
      mx = fmaxf(mx, zv[nt]); mn = fminf(mn, zv[nt]);
    }
#pragma unroll
    for (int o = 1; o < 16; o <<= 1) {
      mx = fmaxf(mx, __shfl_xor(mx, o));
      mn = fminf(mn, __shfl_xor(mn, o));
    }
    float e1[4], e2[4], s1 = 0.f, s2 = 0.f;
#pragma unroll
    for (int nt = 0; nt < 4; ++nt) {
      e1[nt] = __expf(zv[nt] - mx); s1 += e1[nt];
      e2[nt] = __expf(mn - zv[nt]); s2 += e2[nt];
    }
#pragma unroll
    for (int o = 1; o < 16; o <<= 1) { s1 += __shfl_xor(s1, o); s2 += __shfl_xor(s2, o); }
    float r1 = 1.f / s1, r2 = 1.f / s2;
#pragma unroll
    for (int nt = 0; nt < 4; ++nt) {
      E1[r][nt] = fmaxf(e1[nt] * r1, EPSF);
      E2[r][nt] = fmaxf(e2[nt] * r2, EPSF);
    }
  }

  __syncthreads();

  if (!isk) {
#pragma unroll
    for (int r = 0; r < 4; ++r) {
      int row = w * 16 + quad * 4 + r;
#pragma unroll
      for (int nt = 0; nt < 4; ++nt) {
        sX[row * 136 + nt * 16 + txn]      = f2b(E1[r][nt]);
        sX[row * 136 + 64 + nt * 16 + txn] = f2b(E2[r][nt]);
      }
    }
    __syncthreads();
    u16* ob = fqb + ((size_t)(h * NBLK + lt)) * 8192;
    for (int i = 0; i < 4; ++i) {
      int ch = tid + i * 256;
      int row = ch >> 4, f8 = (ch & 15) * 8;
      *(uint4*)(ob + row * 128 + f8) = *(const uint4*)(sX + row * 136 + f8);
    }
  } else {
#pragma unroll
    for (int r = 0; r < 4; ++r) {
      int j = w * 16 + quad * 4 + r;
#pragma unroll
      for (int nt = 0; nt < 4; ++nt) {
        sX[(nt * 16 + txn) * 68 + j]        = f2b(E1[r][nt]);
        sX[(nt * 16 + txn + 64) * 68 + j]   = f2b(E2[r][nt]);
      }
    }
    __syncthreads();
    u16* ob = FKT + (size_t)h * 128 * T_SEQ + lt * 64;
    for (int i = 0; i < 8; ++i) {
      int ch = tid + i * 256;
      int row = ch >> 4, j4 = (ch & 15) * 4;
      *(ushort4*)(ob + (size_t)row * T_SEQ + j4) = *(const ushort4*)(sX + row * 68 + j4);
    }
  }
}

// ---------------- K2: fused state + prefix scan (MFMA, 2 barriers/iter) ----------------
// grid (8 dchunk, 2 fhalf, NH), 256 thr = 4 waves; wave w owns n-tile w (16 f)
__global__ __launch_bounds__(256) void k_scan(
    const u16* __restrict__ FKT, const u16* __restrict__ VT, u16* __restrict__ ST)
{
  __shared__ __align__(16) u16 sVT[16 * 72];
  __shared__ __align__(16) u16 sFK[64 * 72];
  const int dc = blockIdx.x, fh = blockIdx.y, h = blockIdx.z;
  const int tid = threadIdx.x, lane = tid & 63, w = tid >> 6;
  const int quad = lane >> 4, txn = lane & 15;
  const bool doz = (dc == 0);

  bf16x8 vone;
#pragma unroll
  for (int j = 0; j < 8; ++j) vone[j] = (__bf16)1.0f;

  const u16* vbase = VT + ((size_t)((h >> 2) * 128 + dc * 16)) * T_SEQ;
  const u16* fbase = FKT + ((size_t)(h * 128 + fh * 64)) * T_SEQ;

  const int srow = tid >> 4, sj4 = (tid & 15) * 4;
  ushort4 rv, rf[4];
  rv = *(const ushort4*)(vbase + (size_t)srow * T_SEQ + sj4);
#pragma unroll
  for (int i = 0; i < 4; ++i) {
    int ch = tid + i * 256;
    int fr = ch >> 4, fj4 = (ch & 15) * 4;
    rf[i] = *(const ushort4*)(fbase + (size_t)fr * T_SEQ + fj4);
  }

  const f32x4 vzero = {0.f, 0.f, 0.f, 0.f};
  f32x4 acc = vzero, zacc = vzero;

  for (int b = 0; b < NBLK; ++b) {
    __syncthreads();            // prev-iter mfma reads done
    *(ushort4*)(sVT + srow * 72 + sj4) = rv;
#pragma unroll
    for (int i = 0; i < 4; ++i) {
      int ch = tid + i * 256;
      int fr = ch >> 4, fj4 = (ch & 15) * 4;
      *(ushort4*)(sFK + fr * 72 + fj4) = rf[i];
    }
    __syncthreads();
    if (b + 1 < NBLK) {         // prefetch next chunk during mfma + stores
      rv = *(const ushort4*)(vbase + (size_t)srow * T_SEQ + (b + 1) * 64 + sj4);
#pragma unroll
      for (int i = 0; i < 4; ++i) {
        int ch = tid + i * 256;
        int fr = ch >> 4, fj4 = (ch & 15) * 4;
        rf[i] = *(const ushort4*)(fbase + (size_t)fr * T_SEQ + (b + 1) * 64 + fj4);
      }
    }
#pragma unroll
    for (int ks = 0; ks < 2; ++ks) {
      bf16x8 a  = *(const bf16x8*)(sVT + txn * 72 + ks * 32 + quad * 8);
      bf16x8 bb = *(const bf16x8*)(sFK + (w * 16 + txn) * 72 + ks * 32 + quad * 8);
      acc = __builtin_amdgcn_mfma_f32_16x16x32_bf16(a, bb, acc, 0, 0, 0);
      if (doz) zacc = __builtin_amdgcn_mfma_f32_16x16x32_bf16(vone, bb, zacc, 0, 0, 0);
    }
    u16* Sb = ST + (((size_t)(h * NBLK + b)) * 144 + dc * 16) * 128 + fh * 64;
#pragma unroll
    for (int r = 0; r < 4; ++r)
      Sb[(quad * 4 + r) * 128 + w * 16 + txn] = f2b(acc[r]);
    if (doz && quad == 0)
      ST[(((size_t)(h * NBLK + b)) * 144 + 128) * 128 + fh * 64 + w * 16 + txn] = f2b(zacc[0]);
  }
}

// ---------------- K4: main attention (bf16 in-phase staging, no cross-barrier regs) ----------------
// grid (NBLK, NH), 256 threads = 4 waves; wave w owns q-rows [w*16, w*16+16)
__global__ __launch_bounds__(256, 4) void k_main(
    const u16* __restrict__ QB, const u16* __restrict__ KBB,
    const u16* __restrict__ fqb, const u16* __restrict__ ST, const u16* __restrict__ VT,
    const float* __restrict__ wfac, float* __restrict__ out)
{
  __shared__ __align__(16) u16 RA[64 * LDP];   // A-operand: FQ -> Q -> P (K-major rows)
  __shared__ __align__(16) u16 RB[64 * LDP];   // B-operand: S lo/hi -> K[B] -> K[B-1] -> V^T lo/hi
  __shared__ __align__(16) u16 sz[128];        // z row of S_cum
  const int B = blockIdx.x, h = blockIdx.y, tid = threadIdx.x;
  const int lane = tid & 63, w = tid >> 6;
  const int quad = lane >> 4, txn = lane & 15;
  const int arow = w * 16 + txn;
  const int koff = quad * 8;

  const f32x4 vzero = {0.f, 0.f, 0.f, 0.f};
  f32x4 y[8];
#pragma unroll
  for (int t = 0; t < 8; ++t) y[t] = vzero;
  float sln[4] = {0.f, 0.f, 0.f, 0.f};
  const bf16x8 bzero = {0, 0, 0, 0, 0, 0, 0, 0};

  const int kb0 = (B >= 1) ? B - 1 : 0;
  const u16* qtile = QB  + ((size_t)(h * NBLK + B)) * 8192;
  const u16* ktB   = KBB + ((size_t)((h >> 2) * NBLK + B)) * 8192;
  const u16* ktP   = KBB + ((size_t)((h >> 2) * NBLK + kb0)) * 8192;
  const u16* vts   = VT  + (size_t)((h >> 2) * 128) * T_SEQ;

  // ---- linear part: Y += FQ · S_cum[B-2]  (+ z -> sln) ----
  if (B >= 2) {
    const u16* fsrc = fqb + ((size_t)(h * NBLK + B)) * 8192;
    const u16* ssrc = ST + ((size_t)(h * NBLK + (B - 2))) * 18432;
    stage_bf(RA, fsrc, tid);
    stage_bf(RB, ssrc, tid);                 // S^T d-rows 0..63
    if (tid < 32) *(ushort4*)(sz + tid * 4) = *(const ushort4*)(ssrc + 16384 + tid * 4);
    __syncthreads();                         // W1
    f32x4 yz = vzero;
#pragma unroll
    for (int ks = 0; ks < 4; ++ks) {
      bf16x8 a = *(const bf16x8*)(RA + arow * LDP + ks * 32 + koff);
#pragma unroll
      for (int t = 0; t < 4; ++t) {
        bf16x8 bb = *(const bf16x8*)(RB + (t * 16 + txn) * LDP + ks * 32 + koff);
        y[t] = __builtin_amdgcn_mfma_f32_16x16x32_bf16(a, bb, y[t], 0, 0, 0);
      }
      bf16x8 bz = (txn == 0) ? *(const bf16x8*)(sz + ks * 32 + koff) : bzero;
      yz = __builtin_amdgcn_mfma_f32_16x16x32_bf16(a, bz, yz, 0, 0, 0);
    }
    __syncthreads();                         // R1
    stage_bf(RB, ssrc + 8192, tid);          // S^T d-rows 64..127
    __syncthreads();                         // W2
#pragma unroll
    for (int ks = 0; ks < 4; ++ks) {
      bf16x8 a = *(const bf16x8*)(RA + arow * LDP + ks * 32 + koff);
#pragma unroll
      for (int t = 4; t < 8; ++t) {
        bf16x8 bb = *(const bf16x8*)(RB + (t * 16 + txn - 64) * LDP + ks * 32 + koff);
        y[t] = __builtin_amdgcn_mfma_f32_16x16x32_bf16(a, bb, y[t], 0, 0, 0);
      }
    }
#pragma unroll
    for (int r = 0; r < 4; ++r) sln[r] = __shfl(yz[r], lane & 48);  // n==0 lane of quad
    __syncthreads();                         // R2
  }

  // ---- stage Q->RA, K[B]->RB ----
  stage_bf(RA, qtile, tid);
  stage_bf(RB, ktB, tid);
  __syncthreads();                           // W3

  f32x4 s[8];
#pragma unroll
  for (int t = 0; t < 8; ++t) s[t] = vzero;
#pragma unroll
  for (int ks = 0; ks < 4; ++ks) {           // diagonal block -> s[4..7]
    bf16x8 a = *(const bf16x8*)(RA + arow * LDP + ks * 32 + koff);
#pragma unroll
    for (int t = 0; t < 4; ++t) {
      bf16x8 bb = *(const bf16x8*)(RB + (t * 16 + txn) * LDP + ks * 32 + koff);
      s[4 + t] = __builtin_amdgcn_mfma_f32_16x16x32_bf16(a, bb, s[4 + t], 0, 0, 0);
    }
  }

  if (B >= 1) {
    __syncthreads();                         // R3
    stage_bf(RB, ktP, tid);                  // K[B-1]
    __syncthreads();                         // W4
#pragma unroll
    for (int ks = 0; ks < 4; ++ks) {         // previous block -> s[0..3]
      bf16x8 a = *(const bf16x8*)(RA + arow * LDP + ks * 32 + koff);
#pragma unroll
      for (int t = 0; t < 4; ++t) {
        bf16x8 bb = *(const bf16x8*)(RB + (t * 16 + txn) * LDP + ks * 32 + koff);
        s[t] = __builtin_amdgcn_mfma_f32_16x16x32_bf16(a, bb, s[t], 0, 0, 0);
      }
    }
  }

  // ---- masked softmax, write P (bf16) into RA rows (wave-private stripe) ----
  float wf = wfac[h];
  wf = 1.f / (1.f + __expf(-wf));
  const float scale = 0.08838834764831845f;
  float ssum[4];
#pragma unroll
  for (int r = 0; r < 4; ++r) {
    const int irow = w * 16 + quad * 4 + r;
    float sv[8];
    float m = -1e30f;
#pragma unroll
    for (int t = 0; t < 8; ++t) {
      float x = s[t][r] * scale;
      bool msk = (t < 4) ? (B == 0) : ((t - 4) * 16 + txn > irow);
      x = msk ? -1e30f : x;
      sv[t] = x;
      m = fmaxf(m, x);
    }
#pragma unroll
    for (int o = 1; o < 16; o <<= 1) m = fmaxf(m, __shfl_xor(m, o));
    float ss = 0.f;
#pragma unroll
    for (int t = 0; t < 8; ++t) {
      float e = (sv[t] > -1e29f) ? wf * __expf(sv[t] - m) : 0.f;
      ss += e;
      RA[irow * LDP + t * 16 + txn] = f2b(e);
    }
#pragma unroll
    for (int o = 1; o < 16; o <<= 1) ss += __shfl_xor(ss, o);
    ssum[r] = ss;
  }
  __syncthreads();                           // R4: all waves done reading RB

  // ---- V^T lo -> PV t=0..3 ----
  stage_vt(RB, vts, 0, kb0, B, tid);
  __syncthreads();                           // W5
#pragma unroll
  for (int ks = 0; ks < 4; ++ks) {
    if (B == 0 && ks < 2) continue;          // P == 0 on prev-block keys
    bf16x8 a = *(const bf16x8*)(RA + arow * LDP + ks * 32 + koff);
#pragma unroll
    for (int t = 0; t < 4; ++t) {
      bf16x8 bb = *(const bf16x8*)(RB + (t * 16 + txn) * LDP + ks * 32 + koff);
      y[t] = __builtin_amdgcn_mfma_f32_16x16x32_bf16(a, bb, y[t], 0, 0, 0);
    }
  }
  __syncthreads();                           // R5

  // ---- V^T hi -> PV t=4..7 ----
  stage_vt(RB, vts, 64, kb0, B, tid);
  __syncthreads();                           // W6
#pragma unroll
  for (int ks = 0; ks < 4; ++ks) {
    if (B == 0 && ks < 2) continue;
    bf16x8 a = *(const bf16x8*)(RA + arow * LDP + ks * 32 + koff);
#pragma unroll
    for (int t = 4; t < 8; ++t) {
      bf16x8 bb = *(const bf16x8*)(RB + (t * 16 + txn - 64) * LDP + ks * 32 + koff);
      y[t] = __builtin_amdgcn_mfma_f32_16x16x32_bf16(a, bb, y[t], 0, 0, 0);
    }
  }

  // ---- epilogue ----
  const size_t obase = ((size_t)h * T_SEQ + B * 64) * HS;
#pragma unroll
  for (int r = 0; r < 4; ++r) {
    float inv = 1.f / (ssum[r] + sln[r]);
    int irow = w * 16 + quad * 4 + r;
#pragma unroll
    for (int t = 0; t < 8; ++t)
      out[obase + (size_t)irow * HS + t * 16 + txn] = y[t][r] * inv;
  }
}

extern "C" void kernel_launch(void* const* d_in, const int* in_sizes, int n_in,
                              void* d_out, int out_size, void* d_ws, size_t ws_size,
                              hipStream_t stream) {
  const float* q    = (const float*)d_in[0];
  const float* k    = (const float*)d_in[1];
  const float* v    = (const float*)d_in[2];
  const float* wq   = (const float*)d_in[3];
  const float* wk   = (const float*)d_in[4];
  const float* wfac = (const float*)d_in[5];
  float* out = (float*)d_out;
  char* wsb = (char*)d_ws;

  u16* fqb = (u16*)(wsb + FQB_OFF);
  u16* FKT = (u16*)(wsb + FKT_OFF);
  u16* ST  = (u16*)(wsb + ST_OFF);
  u16* VT  = (u16*)(wsb + VT_OFF);
  u16* WT  = (u16*)(wsb + WT_OFF);
  u16* QB  = (u16*)(wsb + QB_OFF);
  u16* KBB = (u16*)(wsb + KB_OFF);

  k_pre  <<<dim3(320),         256, 0, stream>>>(wq, wk, v, WT, VT);
  k_fmap <<<dim3(NBLK, NH, 2), 256, 0, stream>>>(q, k, WT, fqb, FKT, QB, KBB);
  k_scan <<<dim3(8, 2, NH),    256, 0, stream>>>(FKT, VT, ST);
  k_main <<<dim3(NBLK, NH),    256, 0, stream>>>(QB, KBB, fqb, ST, VT, wfac, out);
}